// Round 1
// baseline (1023.083 us; speedup 1.0000x reference)
//
#include <hip/hip_runtime.h>
#include <hip/hip_bf16.h>

typedef __attribute__((ext_vector_type(8))) short bf16x8;
typedef __attribute__((ext_vector_type(4))) float f32x4;

__device__ __forceinline__ unsigned short f2bf(float f) {
  unsigned u = __float_as_uint(f);
  u += 0x7fffu + ((u >> 16) & 1u);   // RNE
  return (unsigned short)(u >> 16);
}

__device__ __forceinline__ void gload16(const void* g, void* l) {
  __builtin_amdgcn_global_load_lds(
      (const __attribute__((address_space(1))) void*)g,
      (__attribute__((address_space(3))) void*)l, 16, 0, 0);
}

// ---------------- fp32 -> bf16 convert ----------------
__global__ void cvt_bf16(const float* __restrict__ in, unsigned short* __restrict__ out, int n4) {
  int i = blockIdx.x * blockDim.x + threadIdx.x;
  int st = gridDim.x * blockDim.x;
  for (; i < n4; i += st) {
    float4 f = ((const float4*)in)[i];
    ushort4 o;
    o.x = f2bf(f.x); o.y = f2bf(f.y); o.z = f2bf(f.z); o.w = f2bf(f.w);
    ((ushort4*)out)[i] = o;
  }
}

// ---------------- GEMM C = A * B^T + bias ----------------
// A [M][K] bf16, B [N][K] bf16. 128x128 tile, BK=64, 4 waves (2x2), 16x16x32 MFMA.
// EPI==0: outF[i*N+j] = acc + bias[j]
// EPI==1: QKV scatter (q bf16 ws, k fp32 out + bf16 ws, v fp32 out + bf16 ws transposed [b,h,d,t])
template<int EPI>
__global__ __launch_bounds__(256) void gemm_bt(
    const unsigned short* __restrict__ A,
    const unsigned short* __restrict__ B,
    const float* __restrict__ bias,
    float* __restrict__ outF,
    unsigned short* __restrict__ q_ws,
    unsigned short* __restrict__ k_ws,
    unsigned short* __restrict__ v_wst,
    float* __restrict__ out_k,
    float* __restrict__ out_v,
    int M, int N, int K)
{
  __shared__ __align__(16) unsigned short As[128 * 64];
  __shared__ __align__(16) unsigned short Bs[128 * 64];

  const int nbx = N >> 7;
  int nwg = gridDim.x;
  int bid = blockIdx.x;
  int cpx = nwg >> 3;                  // nwg % 8 == 0 for all our launches
  int sw  = (bid & 7) * cpx + (bid >> 3);
  int bx = sw % nbx, by = sw / nbx;
  const int m0 = by << 7, n0 = bx << 7;

  const int tid = threadIdx.x, w = tid >> 6, ln = tid & 63;
  const int wm = w >> 1, wn = w & 1;
  const int srow = ln >> 3;            // 0..7
  const int scol = (ln & 7) * 8;       // element offset in K
  const int lg = ln >> 4, lc = ln & 15;

  f32x4 acc[4][4] = {};

  for (int k0 = 0; k0 < K; k0 += 64) {
    __syncthreads();
#pragma unroll
    for (int i = 0; i < 4; ++i) {
      int row = w * 32 + i * 8 + srow;
      gload16(A + (size_t)(m0 + row) * K + k0 + scol, &As[(w * 32 + i * 8) * 64]);
      gload16(B + (size_t)(n0 + row) * K + k0 + scol, &Bs[(w * 32 + i * 8) * 64]);
    }
    __syncthreads();
#pragma unroll
    for (int kk = 0; kk < 2; ++kk) {
      bf16x8 af[4], bfr[4];
      int ko = kk * 32 + lg * 8;
#pragma unroll
      for (int m = 0; m < 4; ++m) af[m]  = *(const bf16x8*)&As[(wm * 64 + m * 16 + lc) * 64 + ko];
#pragma unroll
      for (int n = 0; n < 4; ++n) bfr[n] = *(const bf16x8*)&Bs[(wn * 64 + n * 16 + lc) * 64 + ko];
#pragma unroll
      for (int m = 0; m < 4; ++m)
#pragma unroll
        for (int n = 0; n < 4; ++n)
          acc[m][n] = __builtin_amdgcn_mfma_f32_16x16x32_bf16(af[m], bfr[n], acc[m][n], 0, 0, 0);
    }
  }

  const int lr = lg * 4;
  if (EPI == 0) {
#pragma unroll
    for (int m = 0; m < 4; ++m) {
      int r0 = m0 + wm * 64 + m * 16 + lr;
#pragma unroll
      for (int n = 0; n < 4; ++n) {
        int c = n0 + wn * 64 + n * 16 + lc;
        float bv = bias[c];
#pragma unroll
        for (int r = 0; r < 4; ++r)
          outF[(size_t)(r0 + r) * N + c] = acc[m][n][r] + bv;
      }
    }
  } else {
    const int sel = n0 >> 11;            // 0=q 1=k 2=v (block-uniform)
    const int h   = (n0 >> 7) & 15;      // block-uniform
    const int b   = m0 >> 11;            // block-uniform
    const size_t hb = (size_t)(b * 16 + h);
#pragma unroll
    for (int m = 0; m < 4; ++m) {
      int t0 = (m0 & 2047) + wm * 64 + m * 16 + lr;
#pragma unroll
      for (int n = 0; n < 4; ++n) {
        int d = wn * 64 + n * 16 + lc;
        float bv = bias[n0 + d];
        float v0 = acc[m][n][0] + bv, v1 = acc[m][n][1] + bv;
        float v2 = acc[m][n][2] + bv, v3 = acc[m][n][3] + bv;
        size_t base = (hb * 2048 + t0) * 128 + d;
        if (sel == 0) {
          q_ws[base      ] = f2bf(v0);
          q_ws[base + 128] = f2bf(v1);
          q_ws[base + 256] = f2bf(v2);
          q_ws[base + 384] = f2bf(v3);
        } else if (sel == 1) {
          out_k[base] = v0; out_k[base + 128] = v1; out_k[base + 256] = v2; out_k[base + 384] = v3;
          k_ws[base      ] = f2bf(v0);
          k_ws[base + 128] = f2bf(v1);
          k_ws[base + 256] = f2bf(v2);
          k_ws[base + 384] = f2bf(v3);
        } else {
          out_v[base] = v0; out_v[base + 128] = v1; out_v[base + 256] = v2; out_v[base + 384] = v3;
          ushort4 pk; pk.x = f2bf(v0); pk.y = f2bf(v1); pk.z = f2bf(v2); pk.w = f2bf(v3);
          *(ushort4*)&v_wst[(hb * 128 + d) * 2048 + t0] = pk;   // t0 % 4 == 0 -> 8B aligned
        }
      }
    }
  }
}

// ---------------- flash attention (causal) ----------------
// q_ws,k_ws: [64 bh][2048 t][128 d] bf16 ; v_wst: [64 bh][128 d][2048 t] bf16
// y_ws out: [B=4][T=2048][C=2048] bf16. 4 waves x 32 q-rows, KVBLK=64.
__global__ __launch_bounds__(256) void attn_fwd(
    const unsigned short* __restrict__ q_ws,
    const unsigned short* __restrict__ k_ws,
    const unsigned short* __restrict__ v_wst,
    unsigned short* __restrict__ y_ws)
{
  __shared__ __align__(16) unsigned short K_lds[64 * 128];   // [kv][d], rows 256B, XOR-swizzled
  __shared__ __align__(16) unsigned short Vt_lds[128 * 64];  // [d][kv], rows 128B, XOR-swizzled
  __shared__ __align__(16) unsigned short P_lds[128 * 64];   // [q][kv], rows 128B, XOR-swizzled

  int bid = blockIdx.x;
  int sw = (bid & 7) * 128 + (bid >> 3);    // XCD swizzle (1024 blocks)
  const int bh = sw >> 4;
  const int qb = sw & 15;
  const int q0 = qb << 7;
  const int tid = threadIdx.x, w = tid >> 6, ln = tid & 63;
  const int lg = ln >> 4, lc = ln & 15;
  const int b = bh >> 4, h = bh & 15;

  // Q fragments in registers: rows q0+w*32 .. +31
  bf16x8 qf[2][4];
  {
    const unsigned short* qp = q_ws + ((size_t)bh * 2048 + q0 + w * 32) * 128;
#pragma unroll
    for (int m = 0; m < 2; ++m)
#pragma unroll
      for (int ks = 0; ks < 4; ++ks)
        qf[m][ks] = *(const bf16x8*)&qp[(m * 16 + lc) * 128 + ks * 32 + lg * 8];
  }

  float mrun[2][4], lsum[2][4];
  f32x4 o[2][8] = {};
#pragma unroll
  for (int m = 0; m < 2; ++m)
#pragma unroll
    for (int r = 0; r < 4; ++r) { mrun[m][r] = -3e38f; lsum[m][r] = 0.f; }

  const int ntiles = (q0 >> 6) + 2;
  for (int t = 0; t < ntiles; ++t) {
    const int kv0 = t << 6;
    __syncthreads();
#pragma unroll
    for (int i = 0; i < 4; ++i) {
      // K tile: 4 rows / inst (256B rows); source col pre-swizzled
      int rowK = w * 16 + i * 4 + lg;
      int gK = (lc * 16) ^ ((rowK & 7) << 4);
      gload16(k_ws + ((size_t)bh * 2048 + kv0 + rowK) * 128 + (gK >> 1),
              &K_lds[(w * 16 + i * 4) * 128]);
      // Vt tile: 8 rows / inst (128B rows)
      int rowV = w * 32 + i * 8 + (ln >> 3);
      int gV = ((ln & 7) * 16) ^ ((rowV & 7) << 4);
      gload16(v_wst + ((size_t)bh * 128 + rowV) * 2048 + kv0 + (gV >> 1),
              &Vt_lds[(w * 32 + i * 8) * 64]);
    }
    __syncthreads();
    if (kv0 > q0 + w * 32 + 31) continue;   // tile fully masked for this wave

    // ---- S = Q K^T ----
    f32x4 s[2][4] = {};
#pragma unroll
    for (int ks = 0; ks < 4; ++ks) {
      bf16x8 kb[4];
#pragma unroll
      for (int n = 0; n < 4; ++n) {
        int row = n * 16 + lc;
        int cb = (ks * 64 + lg * 16) ^ ((row & 7) << 4);
        kb[n] = *(const bf16x8*)((const char*)K_lds + row * 256 + cb);
      }
#pragma unroll
      for (int m = 0; m < 2; ++m)
#pragma unroll
        for (int n = 0; n < 4; ++n)
          s[m][n] = __builtin_amdgcn_mfma_f32_16x16x32_bf16(qf[m][ks], kb[n], s[m][n], 0, 0, 0);
    }

    // ---- scale + causal mask ----
    const float sc = 0.08838834764831845f;  // 1/sqrt(128)
#pragma unroll
    for (int m = 0; m < 2; ++m) {
      int rowg = q0 + w * 32 + m * 16 + lg * 4;
#pragma unroll
      for (int n = 0; n < 4; ++n) {
        int colg = kv0 + n * 16 + lc;
#pragma unroll
        for (int r = 0; r < 4; ++r) {
          float v = s[m][n][r] * sc;
          if (colg > rowg + r) v = -1e30f;
          s[m][n][r] = v;
        }
      }
    }

    // ---- online softmax (rows live in 16-lane groups) ----
#pragma unroll
    for (int m = 0; m < 2; ++m) {
#pragma unroll
      for (int r = 0; r < 4; ++r) {
        float mx = fmaxf(fmaxf(s[m][0][r], s[m][1][r]), fmaxf(s[m][2][r], s[m][3][r]));
        mx = fmaxf(mx, __shfl_xor(mx, 1));
        mx = fmaxf(mx, __shfl_xor(mx, 2));
        mx = fmaxf(mx, __shfl_xor(mx, 4));
        mx = fmaxf(mx, __shfl_xor(mx, 8));
        float mn = fmaxf(mrun[m][r], mx);
        float al = __expf(mrun[m][r] - mn);
        mrun[m][r] = mn;
        float ps = 0.f;
#pragma unroll
        for (int n = 0; n < 4; ++n) {
          float p = __expf(s[m][n][r] - mn);
          s[m][n][r] = p;
          ps += p;
        }
        ps += __shfl_xor(ps, 1);
        ps += __shfl_xor(ps, 2);
        ps += __shfl_xor(ps, 4);
        ps += __shfl_xor(ps, 8);
        lsum[m][r] = lsum[m][r] * al + ps;
#pragma unroll
        for (int n8 = 0; n8 < 8; ++n8) o[m][n8][r] *= al;
      }
    }

    // ---- P -> LDS (bf16, swizzled; each wave touches only its own 32 rows) ----
#pragma unroll
    for (int m = 0; m < 2; ++m)
#pragma unroll
      for (int n = 0; n < 4; ++n)
#pragma unroll
        for (int r = 0; r < 4; ++r) {
          int row = w * 32 + m * 16 + lg * 4 + r;
          int cb = ((n * 16 + lc) * 2) ^ ((row & 7) << 4);
          *(unsigned short*)((char*)P_lds + row * 128 + cb) = f2bf(s[m][n][r]);
        }

    // ---- O += P V ----
#pragma unroll
    for (int ks = 0; ks < 2; ++ks) {
      bf16x8 pa[2], vb[8];
#pragma unroll
      for (int m = 0; m < 2; ++m) {
        int row = w * 32 + m * 16 + lc;
        int cb = (ks * 64 + lg * 16) ^ ((row & 7) << 4);
        pa[m] = *(const bf16x8*)((const char*)P_lds + row * 128 + cb);
      }
#pragma unroll
      for (int n8 = 0; n8 < 8; ++n8) {
        int row = n8 * 16 + lc;
        int cb = (ks * 64 + lg * 16) ^ ((row & 7) << 4);
        vb[n8] = *(const bf16x8*)((const char*)Vt_lds + row * 128 + cb);
      }
#pragma unroll
      for (int m = 0; m < 2; ++m)
#pragma unroll
        for (int n8 = 0; n8 < 8; ++n8)
          o[m][n8] = __builtin_amdgcn_mfma_f32_16x16x32_bf16(pa[m], vb[n8], o[m][n8], 0, 0, 0);
    }
  }

  // ---- normalize + write y_ws [B][T][C] bf16 ----
  float inv[2][4];
#pragma unroll
  for (int m = 0; m < 2; ++m)
#pragma unroll
    for (int r = 0; r < 4; ++r) inv[m][r] = 1.f / lsum[m][r];
  const size_t bb = (size_t)b * 2048;
#pragma unroll
  for (int m = 0; m < 2; ++m)
#pragma unroll
    for (int n8 = 0; n8 < 8; ++n8)
#pragma unroll
      for (int r = 0; r < 4; ++r) {
        int rowg = q0 + w * 32 + m * 16 + lg * 4 + r;
        int colg = h * 128 + n8 * 16 + lc;
        y_ws[(bb + rowg) * 2048 + colg] = f2bf(o[m][n8][r] * inv[m][r]);
      }
}

// ---------------- launch ----------------
extern "C" void kernel_launch(void* const* d_in, const int* in_sizes, int n_in,
                              void* d_out, int out_size, void* d_ws, size_t ws_size,
                              hipStream_t stream) {
  const float* x    = (const float*)d_in[0];
  const float* Wqkv = (const float*)d_in[1];
  const float* bqkv = (const float*)d_in[2];
  const float* Wout = (const float*)d_in[3];
  const float* bout = (const float*)d_in[4];

  float* y_out = (float*)d_out;                       // [4,2048,2048]
  float* k_out = y_out + (size_t)16777216;            // [4,16,2048,128]
  float* v_out = y_out + (size_t)33554432;            // [4,16,2048,128]

  unsigned short* xb    = (unsigned short*)d_ws;      // 16,777,216
  unsigned short* wqkvb = xb + 16777216;              // 12,582,912
  unsigned short* woutb = wqkvb + 12582912;           //  4,194,304
  unsigned short* q_ws  = woutb + 4194304;            // 16,777,216  [bh][t][d]
  unsigned short* k_ws  = q_ws + 16777216;            // 16,777,216  [bh][t][d]
  unsigned short* v_wst = k_ws + 16777216;            // 16,777,216  [bh][d][t]
  unsigned short* y_ws  = v_wst + 16777216;           // 16,777,216  [b][t][c]

  cvt_bf16<<<2048, 256, 0, stream>>>(x, xb, 16777216 / 4);
  cvt_bf16<<<2048, 256, 0, stream>>>(Wqkv, wqkvb, 12582912 / 4);
  cvt_bf16<<<1024, 256, 0, stream>>>(Wout, woutb, 4194304 / 4);

  gemm_bt<1><<<3072, 256, 0, stream>>>(xb, wqkvb, bqkv, nullptr,
                                       q_ws, k_ws, v_wst, k_out, v_out,
                                       8192, 6144, 2048);

  attn_fwd<<<1024, 256, 0, stream>>>(q_ws, k_ws, v_wst, y_ws);

  gemm_bt<0><<<1024, 256, 0, stream>>>(y_ws, woutb, bout, y_out,
                                       nullptr, nullptr, nullptr, nullptr, nullptr,
                                       8192, 2048, 2048);
}

// Round 2
// 845.408 us; speedup vs baseline: 1.2102x; 1.2102x over previous
//
#include <hip/hip_runtime.h>
#include <hip/hip_bf16.h>

typedef __attribute__((ext_vector_type(8))) short bf16x8;
typedef __attribute__((ext_vector_type(4))) float f32x4;

__device__ __forceinline__ unsigned short f2bf(float f) {
  unsigned u = __float_as_uint(f);
  u += 0x7fffu + ((u >> 16) & 1u);   // RNE
  return (unsigned short)(u >> 16);
}

__device__ __forceinline__ void gload16(const void* g, void* l) {
  __builtin_amdgcn_global_load_lds(
      (const __attribute__((address_space(1))) void*)g,
      (__attribute__((address_space(3))) void*)l, 16, 0, 0);
}

// ---------------- fp32 -> bf16 convert ----------------
__global__ void cvt_bf16(const float* __restrict__ in, unsigned short* __restrict__ out, int n4) {
  int i = blockIdx.x * blockDim.x + threadIdx.x;
  int st = gridDim.x * blockDim.x;
  for (; i < n4; i += st) {
    float4 f = ((const float4*)in)[i];
    ushort4 o;
    o.x = f2bf(f.x); o.y = f2bf(f.y); o.z = f2bf(f.z); o.w = f2bf(f.w);
    ((ushort4*)out)[i] = o;
  }
}

// ---------------- GEMM C = A * B^T + bias (double-buffered staging) ----------------
// A [M][K] bf16, B [N][K] bf16. 128x128 tile, BK=64, 4 waves (2x2), 16x16x32 MFMA.
template<int EPI>
__global__ __launch_bounds__(256) void gemm_bt(
    const unsigned short* __restrict__ A,
    const unsigned short* __restrict__ B,
    const float* __restrict__ bias,
    float* __restrict__ outF,
    unsigned short* __restrict__ q_ws,
    unsigned short* __restrict__ k_ws,
    unsigned short* __restrict__ v_wst,
    float* __restrict__ out_k,
    float* __restrict__ out_v,
    int M, int N, int K)
{
  __shared__ __align__(16) unsigned short As[2][128 * 64];
  __shared__ __align__(16) unsigned short Bs[2][128 * 64];

  const int nbx = N >> 7;
  int nwg = gridDim.x;
  int bid = blockIdx.x;
  int cpx = nwg >> 3;                  // nwg % 8 == 0 for all our launches
  int sw  = (bid & 7) * cpx + (bid >> 3);
  int bx = sw % nbx, by = sw / nbx;
  const int m0 = by << 7, n0 = bx << 7;

  const int tid = threadIdx.x, w = tid >> 6, ln = tid & 63;
  const int wm = w >> 1, wn = w & 1;
  const int srow = ln >> 3;            // 0..7
  const int scol = (ln & 7) * 8;       // element offset in K
  const int lg = ln >> 4, lc = ln & 15;

  f32x4 acc[4][4] = {};

  auto STAGE = [&](int bf, int k0) {
#pragma unroll
    for (int i = 0; i < 4; ++i) {
      int row = w * 32 + i * 8 + srow;
      gload16(A + (size_t)(m0 + row) * K + k0 + scol, &As[bf][(w * 32 + i * 8) * 64]);
      gload16(B + (size_t)(n0 + row) * K + k0 + scol, &Bs[bf][(w * 32 + i * 8) * 64]);
    }
  };

  const int nt = K >> 6;
  STAGE(0, 0);
  for (int t = 0; t < nt; ++t) {
    __syncthreads();                     // drains vmcnt: buf[t&1] fully staged for ALL waves
    if (t + 1 < nt) STAGE((t + 1) & 1, (t + 1) << 6);   // fly during compute
    const unsigned short* as = As[t & 1];
    const unsigned short* bs = Bs[t & 1];
#pragma unroll
    for (int kk = 0; kk < 2; ++kk) {
      bf16x8 af[4], bfr[4];
      int ko = kk * 32 + lg * 8;
#pragma unroll
      for (int m = 0; m < 4; ++m) af[m]  = *(const bf16x8*)&as[(wm * 64 + m * 16 + lc) * 64 + ko];
#pragma unroll
      for (int n = 0; n < 4; ++n) bfr[n] = *(const bf16x8*)&bs[(wn * 64 + n * 16 + lc) * 64 + ko];
#pragma unroll
      for (int m = 0; m < 4; ++m)
#pragma unroll
        for (int n = 0; n < 4; ++n)
          acc[m][n] = __builtin_amdgcn_mfma_f32_16x16x32_bf16(af[m], bfr[n], acc[m][n], 0, 0, 0);
    }
  }

  const int lr = lg * 4;
  if (EPI == 0) {
#pragma unroll
    for (int m = 0; m < 4; ++m) {
      int r0 = m0 + wm * 64 + m * 16 + lr;
#pragma unroll
      for (int n = 0; n < 4; ++n) {
        int c = n0 + wn * 64 + n * 16 + lc;
        float bv = bias[c];
#pragma unroll
        for (int r = 0; r < 4; ++r)
          outF[(size_t)(r0 + r) * N + c] = acc[m][n][r] + bv;
      }
    }
  } else {
    const int sel = n0 >> 11;            // 0=q 1=k 2=v (block-uniform)
    const int h   = (n0 >> 7) & 15;      // block-uniform
    const int b   = m0 >> 11;            // block-uniform
    const size_t hb = (size_t)(b * 16 + h);
#pragma unroll
    for (int m = 0; m < 4; ++m) {
      int t0 = (m0 & 2047) + wm * 64 + m * 16 + lr;
#pragma unroll
      for (int n = 0; n < 4; ++n) {
        int d = wn * 64 + n * 16 + lc;
        float bv = bias[n0 + d];
        float v0 = acc[m][n][0] + bv, v1 = acc[m][n][1] + bv;
        float v2 = acc[m][n][2] + bv, v3 = acc[m][n][3] + bv;
        size_t base = (hb * 2048 + t0) * 128 + d;
        if (sel == 0) {
          q_ws[base      ] = f2bf(v0);
          q_ws[base + 128] = f2bf(v1);
          q_ws[base + 256] = f2bf(v2);
          q_ws[base + 384] = f2bf(v3);
        } else if (sel == 1) {
          out_k[base] = v0; out_k[base + 128] = v1; out_k[base + 256] = v2; out_k[base + 384] = v3;
          k_ws[base      ] = f2bf(v0);
          k_ws[base + 128] = f2bf(v1);
          k_ws[base + 256] = f2bf(v2);
          k_ws[base + 384] = f2bf(v3);
        } else {
          out_v[base] = v0; out_v[base + 128] = v1; out_v[base + 256] = v2; out_v[base + 384] = v3;
          ushort4 pk; pk.x = f2bf(v0); pk.y = f2bf(v1); pk.z = f2bf(v2); pk.w = f2bf(v3);
          *(ushort4*)&v_wst[(hb * 128 + d) * 2048 + t0] = pk;   // t0 % 4 == 0 -> 8B aligned
        }
      }
    }
  }
}

// ---------------- flash attention (causal, swapped QK^T, fixed-max softmax) ----------------
// q_ws,k_ws: [64 bh][2048 t][128 d] bf16 ; v_wst: [64 bh][128 d][2048 t] bf16
// y_ws out: [B=4][T=2048][C=2048] bf16. 4 waves x 32 q-rows, KVBLK=64, dbuf K/Vt staging.
__global__ __launch_bounds__(256) void attn_fwd(
    const unsigned short* __restrict__ q_ws,
    const unsigned short* __restrict__ k_ws,
    const unsigned short* __restrict__ v_wst,
    unsigned short* __restrict__ y_ws)
{
  __shared__ __align__(16) unsigned short K_lds[2][64 * 128];   // [kv][d], 256B rows, swizzled
  __shared__ __align__(16) unsigned short Vt_lds[2][128 * 64];  // [d][kv], 128B rows, swizzled
  __shared__ __align__(16) unsigned short P_lds[128 * 64];      // [q][kv], 128B rows, swizzled

  int bid = blockIdx.x;
  int sw = (bid & 7) * 128 + (bid >> 3);    // XCD swizzle (1024 blocks)
  const int bh = sw >> 4;
  const int qb = sw & 15;
  const int q0 = qb << 7;
  const int tid = threadIdx.x, w = tid >> 6, ln = tid & 63;
  const int lg = ln >> 4, lc = ln & 15;
  const int b = bh >> 4, h = bh & 15;

  // Q fragments in registers (B-operand layout of swapped mfma == old A-operand layout)
  bf16x8 qf[2][4];
  {
    const unsigned short* qp = q_ws + ((size_t)bh * 2048 + q0 + w * 32) * 128;
#pragma unroll
    for (int m = 0; m < 2; ++m)
#pragma unroll
      for (int ks = 0; ks < 4; ++ks)
        qf[m][ks] = *(const bf16x8*)&qp[(m * 16 + lc) * 128 + ks * 32 + lg * 8];
  }

  float lsum[2] = {0.f, 0.f};
  f32x4 o[2][8] = {};   // O^T: rows d (n8,lg,r), cols q (m,lc)

  auto STAGE = [&](int bf, int kv0) {
#pragma unroll
    for (int i = 0; i < 4; ++i) {
      int rowK = w * 16 + i * 4 + lg;
      int gK = (lc * 16) ^ ((rowK & 7) << 4);
      gload16(k_ws + ((size_t)bh * 2048 + kv0 + rowK) * 128 + (gK >> 1),
              &K_lds[bf][(w * 16 + i * 4) * 128]);
      int rowV = w * 32 + i * 8 + (ln >> 3);
      int gV = ((ln & 7) * 16) ^ ((rowV & 7) << 4);
      gload16(v_wst + ((size_t)bh * 128 + rowV) * 2048 + kv0 + (gV >> 1),
              &Vt_lds[bf][(w * 32 + i * 8) * 64]);
    }
  };

  const int ntiles = (q0 >> 6) + 2;
  STAGE(0, 0);
  const float scl = 0.08838834764831845f;  // 1/sqrt(128)

  for (int t = 0; t < ntiles; ++t) {
    const int kv0 = t << 6;
    __syncthreads();                         // buf[t&1] staged for all waves
    if (t + 1 < ntiles) STAGE((t + 1) & 1, (t + 1) << 6);
    if (kv0 > q0 + w * 32 + 31) continue;    // tile fully masked for this wave
    const unsigned short* Kl = K_lds[t & 1];
    const unsigned short* Vl = Vt_lds[t & 1];

    // ---- S^T = K Q^T : lane holds kv = n*16+lg*4+r, q = m*16+lc ----
    f32x4 s[2][4] = {};
#pragma unroll
    for (int ks = 0; ks < 4; ++ks) {
      bf16x8 kb[4];
#pragma unroll
      for (int n = 0; n < 4; ++n) {
        int row = n * 16 + lc;
        int cb = (ks * 64 + lg * 16) ^ ((row & 7) << 4);
        kb[n] = *(const bf16x8*)((const char*)Kl + row * 256 + cb);
      }
#pragma unroll
      for (int m = 0; m < 2; ++m)
#pragma unroll
        for (int n = 0; n < 4; ++n)
          s[m][n] = __builtin_amdgcn_mfma_f32_16x16x32_bf16(kb[n], qf[m][ks], s[m][n], 0, 0, 0);
    }

    // ---- mask + exp (fixed max) + per-lane partial row sums + P -> LDS (b64) ----
#pragma unroll
    for (int m = 0; m < 2; ++m) {
      const int rowg = q0 + w * 32 + m * 16 + lc;
      const int prow = w * 32 + m * 16 + lc;
      const unsigned swz = (unsigned)((prow & 7) << 4);
#pragma unroll
      for (int n = 0; n < 4; ++n) {
        const int colg = kv0 + n * 16 + lg * 4;
        float p0 = (colg + 0 > rowg) ? 0.f : __expf(s[m][n][0] * scl);
        float p1 = (colg + 1 > rowg) ? 0.f : __expf(s[m][n][1] * scl);
        float p2 = (colg + 2 > rowg) ? 0.f : __expf(s[m][n][2] * scl);
        float p3 = (colg + 3 > rowg) ? 0.f : __expf(s[m][n][3] * scl);
        lsum[m] += (p0 + p1) + (p2 + p3);
        ushort4 pk;
        pk.x = f2bf(p0); pk.y = f2bf(p1); pk.z = f2bf(p2); pk.w = f2bf(p3);
        *(ushort4*)((char*)P_lds + prow * 128 + ((unsigned)(n * 32 + lg * 8) ^ swz)) = pk;
      }
    }

    // ---- O^T += V^T P^T ----
#pragma unroll
    for (int ks = 0; ks < 2; ++ks) {
      bf16x8 pbf[2], vb[8];
#pragma unroll
      for (int m = 0; m < 2; ++m) {
        int prow = w * 32 + m * 16 + lc;
        int cb = (ks * 64 + lg * 16) ^ ((prow & 7) << 4);
        pbf[m] = *(const bf16x8*)((const char*)P_lds + prow * 128 + cb);
      }
#pragma unroll
      for (int n8 = 0; n8 < 8; ++n8) {
        int row = n8 * 16 + lc;
        int cb = (ks * 64 + lg * 16) ^ ((row & 7) << 4);
        vb[n8] = *(const bf16x8*)((const char*)Vl + row * 128 + cb);
      }
#pragma unroll
      for (int m = 0; m < 2; ++m)
#pragma unroll
        for (int n8 = 0; n8 < 8; ++n8)
          o[m][n8] = __builtin_amdgcn_mfma_f32_16x16x32_bf16(vb[n8], pbf[m], o[m][n8], 0, 0, 0);
    }
  }

  // ---- final row-sum reduce + normalize + write y_ws (contiguous ushort4) ----
  float inv[2];
#pragma unroll
  for (int m = 0; m < 2; ++m) {
    float ls = lsum[m];
    ls += __shfl_xor(ls, 16);
    ls += __shfl_xor(ls, 32);
    inv[m] = 1.f / ls;
  }
  const size_t bb = (size_t)b * 2048;
#pragma unroll
  for (int m = 0; m < 2; ++m) {
    int rowg = q0 + w * 32 + m * 16 + lc;
    unsigned short* yp = y_ws + (bb + rowg) * 2048 + h * 128;
#pragma unroll
    for (int n8 = 0; n8 < 8; ++n8) {
      ushort4 pk;
      pk.x = f2bf(o[m][n8][0] * inv[m]);
      pk.y = f2bf(o[m][n8][1] * inv[m]);
      pk.z = f2bf(o[m][n8][2] * inv[m]);
      pk.w = f2bf(o[m][n8][3] * inv[m]);
      *(ushort4*)&yp[n8 * 16 + lg * 4] = pk;
    }
  }
}

// ---------------- launch ----------------
extern "C" void kernel_launch(void* const* d_in, const int* in_sizes, int n_in,
                              void* d_out, int out_size, void* d_ws, size_t ws_size,
                              hipStream_t stream) {
  const float* x    = (const float*)d_in[0];
  const float* Wqkv = (const float*)d_in[1];
  const float* bqkv = (const float*)d_in[2];
  const float* Wout = (const float*)d_in[3];
  const float* bout = (const float*)d_in[4];

  float* y_out = (float*)d_out;                       // [4,2048,2048]
  float* k_out = y_out + (size_t)16777216;            // [4,16,2048,128]
  float* v_out = y_out + (size_t)33554432;            // [4,16,2048,128]

  unsigned short* xb    = (unsigned short*)d_ws;      // 16,777,216
  unsigned short* wqkvb = xb + 16777216;              // 12,582,912
  unsigned short* woutb = wqkvb + 12582912;           //  4,194,304
  unsigned short* q_ws  = woutb + 4194304;            // 16,777,216  [bh][t][d]
  unsigned short* k_ws  = q_ws + 16777216;            // 16,777,216  [bh][t][d]
  unsigned short* v_wst = k_ws + 16777216;            // 16,777,216  [bh][d][t]
  unsigned short* y_ws  = v_wst + 16777216;           // 16,777,216  [b][t][c]

  cvt_bf16<<<2048, 256, 0, stream>>>(x, xb, 16777216 / 4);
  cvt_bf16<<<2048, 256, 0, stream>>>(Wqkv, wqkvb, 12582912 / 4);
  cvt_bf16<<<1024, 256, 0, stream>>>(Wout, woutb, 4194304 / 4);

  gemm_bt<1><<<3072, 256, 0, stream>>>(xb, wqkvb, bqkv, nullptr,
                                       q_ws, k_ws, v_wst, k_out, v_out,
                                       8192, 6144, 2048);

  attn_fwd<<<1024, 256, 0, stream>>>(q_ws, k_ws, v_wst, y_ws);

  gemm_bt<0><<<1024, 256, 0, stream>>>(y_ws, woutb, bout, y_out,
                                       nullptr, nullptr, nullptr, nullptr, nullptr,
                                       8192, 2048, 2048);
}

// Round 3
// 740.124 us; speedup vs baseline: 1.3823x; 1.1423x over previous
//
#include <hip/hip_runtime.h>
#include <hip/hip_bf16.h>

typedef __attribute__((ext_vector_type(8))) short bf16x8;
typedef __attribute__((ext_vector_type(4))) float f32x4;

__device__ __forceinline__ unsigned short f2bf(float f) {
  unsigned u = __float_as_uint(f);
  u += 0x7fffu + ((u >> 16) & 1u);   // RNE
  return (unsigned short)(u >> 16);
}

__device__ __forceinline__ void gload16(const void* g, void* l) {
  __builtin_amdgcn_global_load_lds(
      (const __attribute__((address_space(1))) void*)g,
      (__attribute__((address_space(3))) void*)l, 16, 0, 0);
}

// ---------------- fp32 -> bf16 convert ----------------
__global__ void cvt_bf16(const float* __restrict__ in, unsigned short* __restrict__ out, int n4) {
  int i = blockIdx.x * blockDim.x + threadIdx.x;
  int st = gridDim.x * blockDim.x;
  for (; i < n4; i += st) {
    float4 f = ((const float4*)in)[i];
    ushort4 o;
    o.x = f2bf(f.x); o.y = f2bf(f.y); o.z = f2bf(f.z); o.w = f2bf(f.w);
    ((ushort4*)out)[i] = o;
  }
}

// ---------------- GEMM C = A * B^T + bias ----------------
// 256x256 tile, BK=64, 8 waves (2M x 4N), counted-vmcnt pipeline, T2 swizzle.
// Protocol per K-tile t:
//   STAGE(T(t+1)) ; s_waitcnt vmcnt(8)  -> all of T(t) landed (in-order retire)
//   s_barrier                            -> collective: every wave's T(t) landed
//   4 quadrant phases {ds_read frags ; setprio(1) ; 16 MFMA ; setprio(0)}
//   s_barrier                            -> slot (t+1)&1 free for next STAGE
// Loads for T(t+1) stay in flight across both barriers (never vmcnt(0) mid-loop).
template<int EPI>
__global__ __launch_bounds__(512, 2) void gemm_bt(
    const unsigned short* __restrict__ A,
    const unsigned short* __restrict__ B,
    const float* __restrict__ bias,
    float* __restrict__ outF,
    unsigned short* __restrict__ q_ws,
    unsigned short* __restrict__ k_ws,
    unsigned short* __restrict__ v_wst,
    float* __restrict__ out_k,
    float* __restrict__ out_v,
    int M, int N, int K)
{
  __shared__ __align__(16) unsigned short As[2][16384];   // [256 rows][64 k] swizzled
  __shared__ __align__(16) unsigned short Bs[2][16384];

  const int nbx = N >> 8;
  int nwg = gridDim.x;
  int bid = blockIdx.x;
  int cpx = nwg >> 3;                  // nwg % 8 == 0 for all our launches
  int sw  = (bid & 7) * cpx + (bid >> 3);
  int bx = sw % nbx, by = sw / nbx;
  const int m0 = by << 8, n0 = bx << 8;

  const int tid = threadIdx.x, w = tid >> 6, ln = tid & 63;
  const int wm = w >> 2, wn = w & 3;   // 2 x 4 wave grid; wave owns 128x64 of C
  const int lg = ln >> 4, lc = ln & 15;

  // staging coords: thread stages 16B; row = i*64 + (tid>>3); 16B-slot = (ln&7)^(row&7)
  const int srow = tid >> 3;                    // 0..63
  const int scol = ((ln & 7) ^ (srow & 7)) * 8; // pre-swizzled source col (elements)

  f32x4 acc[8][4] = {};

  auto STAGE = [&](int bf, int k0) {
#pragma unroll
    for (int i = 0; i < 4; ++i)
      gload16(A + (size_t)(m0 + i * 64 + srow) * K + k0 + scol,
              &As[bf][i * 4096 + w * 512]);
#pragma unroll
    for (int i = 0; i < 4; ++i)
      gload16(B + (size_t)(n0 + i * 64 + srow) * K + k0 + scol,
              &Bs[bf][i * 4096 + w * 512]);
  };

  // swizzled fragment reads: row r, k-slice ks (0..1), 16B slot (ks*4+lg)^(r&7)
  auto rdA = [&](const unsigned short* as, int mh, int mf, int ks) -> bf16x8 {
    int r = wm * 128 + mh * 64 + mf * 16 + lc;
    int cb = (ks * 64 + lg * 16) ^ ((r & 7) << 4);
    return *(const bf16x8*)((const char*)as + r * 128 + cb);
  };
  auto rdB = [&](const unsigned short* bs, int nh, int nf, int ks) -> bf16x8 {
    int r = wn * 64 + (nh * 2 + nf) * 16 + lc;
    int cb = (ks * 64 + lg * 16) ^ ((r & 7) << 4);
    return *(const bf16x8*)((const char*)bs + r * 128 + cb);
  };

  const int nt = K >> 6;
  STAGE(0, 0);
  for (int t = 0; t < nt; ++t) {
    const unsigned short* as = As[t & 1];
    const unsigned short* bs = Bs[t & 1];
    if (t + 1 < nt) {
      STAGE((t + 1) & 1, (t + 1) << 6);
      asm volatile("s_waitcnt vmcnt(8)" ::: "memory");
    } else {
      asm volatile("s_waitcnt vmcnt(0)" ::: "memory");
    }
    __builtin_amdgcn_sched_barrier(0);
    asm volatile("s_barrier" ::: "memory");     // bar1: tile t visible to all
    __builtin_amdgcn_sched_barrier(0);

    bf16x8 a[4][2], b[2][2];
    // ---- P1: quadrant (mh=0, nh=0) ----
#pragma unroll
    for (int mf = 0; mf < 4; ++mf)
#pragma unroll
      for (int ks = 0; ks < 2; ++ks) a[mf][ks] = rdA(as, 0, mf, ks);
#pragma unroll
    for (int nf = 0; nf < 2; ++nf)
#pragma unroll
      for (int ks = 0; ks < 2; ++ks) b[nf][ks] = rdB(bs, 0, nf, ks);
    __builtin_amdgcn_s_setprio(1);
#pragma unroll
    for (int ks = 0; ks < 2; ++ks)
#pragma unroll
      for (int mf = 0; mf < 4; ++mf)
#pragma unroll
        for (int nf = 0; nf < 2; ++nf)
          acc[mf][nf] = __builtin_amdgcn_mfma_f32_16x16x32_bf16(a[mf][ks], b[nf][ks], acc[mf][nf], 0, 0, 0);
    __builtin_amdgcn_s_setprio(0);
    // ---- P2: (mh=0, nh=1) ----
#pragma unroll
    for (int nf = 0; nf < 2; ++nf)
#pragma unroll
      for (int ks = 0; ks < 2; ++ks) b[nf][ks] = rdB(bs, 1, nf, ks);
    __builtin_amdgcn_s_setprio(1);
#pragma unroll
    for (int ks = 0; ks < 2; ++ks)
#pragma unroll
      for (int mf = 0; mf < 4; ++mf)
#pragma unroll
        for (int nf = 0; nf < 2; ++nf)
          acc[mf][2 + nf] = __builtin_amdgcn_mfma_f32_16x16x32_bf16(a[mf][ks], b[nf][ks], acc[mf][2 + nf], 0, 0, 0);
    __builtin_amdgcn_s_setprio(0);
    // ---- P3: (mh=1, nh=1) ----
#pragma unroll
    for (int mf = 0; mf < 4; ++mf)
#pragma unroll
      for (int ks = 0; ks < 2; ++ks) a[mf][ks] = rdA(as, 1, mf, ks);
    __builtin_amdgcn_s_setprio(1);
#pragma unroll
    for (int ks = 0; ks < 2; ++ks)
#pragma unroll
      for (int mf = 0; mf < 4; ++mf)
#pragma unroll
        for (int nf = 0; nf < 2; ++nf)
          acc[4 + mf][2 + nf] = __builtin_amdgcn_mfma_f32_16x16x32_bf16(a[mf][ks], b[nf][ks], acc[4 + mf][2 + nf], 0, 0, 0);
    __builtin_amdgcn_s_setprio(0);
    // ---- P4: (mh=1, nh=0) ----
#pragma unroll
    for (int nf = 0; nf < 2; ++nf)
#pragma unroll
      for (int ks = 0; ks < 2; ++ks) b[nf][ks] = rdB(bs, 0, nf, ks);
    __builtin_amdgcn_s_setprio(1);
#pragma unroll
    for (int ks = 0; ks < 2; ++ks)
#pragma unroll
      for (int mf = 0; mf < 4; ++mf)
#pragma unroll
        for (int nf = 0; nf < 2; ++nf)
          acc[4 + mf][nf] = __builtin_amdgcn_mfma_f32_16x16x32_bf16(a[mf][ks], b[nf][ks], acc[4 + mf][nf], 0, 0, 0);
    __builtin_amdgcn_s_setprio(0);

    __builtin_amdgcn_sched_barrier(0);
    asm volatile("s_barrier" ::: "memory");     // bar2: reads of tile t done
    __builtin_amdgcn_sched_barrier(0);
  }

  if (EPI == 0) {
#pragma unroll
    for (int m8 = 0; m8 < 8; ++m8) {
      int r0 = m0 + wm * 128 + m8 * 16 + lg * 4;
#pragma unroll
      for (int n4 = 0; n4 < 4; ++n4) {
        int c = n0 + wn * 64 + n4 * 16 + lc;
        float bv = bias[c];
#pragma unroll
        for (int r = 0; r < 4; ++r)
          outF[(size_t)(r0 + r) * N + c] = acc[m8][n4][r] + bv;
      }
    }
  } else {
    const int sel = n0 >> 11;            // 0=q 1=k 2=v (block-uniform: 256 | 2048)
    const int b_  = m0 >> 11;
#pragma unroll
    for (int m8 = 0; m8 < 8; ++m8) {
      int t0 = (m0 & 2047) + wm * 128 + m8 * 16 + lg * 4;
#pragma unroll
      for (int n4 = 0; n4 < 4; ++n4) {
        int dg = n0 + wn * 64 + n4 * 16 + lc;
        int h  = (dg >> 7) & 15;
        int d  = dg & 127;
        const size_t hb = (size_t)(b_ * 16 + h);
        float bv = bias[dg];
        float v0 = acc[m8][n4][0] + bv, v1 = acc[m8][n4][1] + bv;
        float v2 = acc[m8][n4][2] + bv, v3 = acc[m8][n4][3] + bv;
        size_t base = (hb * 2048 + t0) * 128 + d;
        if (sel == 0) {
          q_ws[base      ] = f2bf(v0);
          q_ws[base + 128] = f2bf(v1);
          q_ws[base + 256] = f2bf(v2);
          q_ws[base + 384] = f2bf(v3);
        } else if (sel == 1) {
          out_k[base] = v0; out_k[base + 128] = v1; out_k[base + 256] = v2; out_k[base + 384] = v3;
          k_ws[base      ] = f2bf(v0);
          k_ws[base + 128] = f2bf(v1);
          k_ws[base + 256] = f2bf(v2);
          k_ws[base + 384] = f2bf(v3);
        } else {
          out_v[base] = v0; out_v[base + 128] = v1; out_v[base + 256] = v2; out_v[base + 384] = v3;
          ushort4 pk; pk.x = f2bf(v0); pk.y = f2bf(v1); pk.z = f2bf(v2); pk.w = f2bf(v3);
          *(ushort4*)&v_wst[(hb * 128 + d) * 2048 + t0] = pk;   // t0 % 4 == 0
        }
      }
    }
  }
}

// ---------------- flash attention (causal, swapped QK^T, fixed-max softmax) ----------------
// q_ws,k_ws: [64 bh][2048 t][128 d] bf16 ; v_wst: [64 bh][128 d][2048 t] bf16
// y_ws out: [B=4][T=2048][C=2048] bf16. 4 waves x 32 q-rows, KVBLK=64, dbuf K/Vt staging.
__global__ __launch_bounds__(256) void attn_fwd(
    const unsigned short* __restrict__ q_ws,
    const unsigned short* __restrict__ k_ws,
    const unsigned short* __restrict__ v_wst,
    unsigned short* __restrict__ y_ws)
{
  __shared__ __align__(16) unsigned short K_lds[2][64 * 128];   // [kv][d], 256B rows, swizzled
  __shared__ __align__(16) unsigned short Vt_lds[2][128 * 64];  // [d][kv], 128B rows, swizzled
  __shared__ __align__(16) unsigned short P_lds[128 * 64];      // [q][kv], 128B rows, swizzled

  int bid = blockIdx.x;
  int sw = (bid & 7) * 128 + (bid >> 3);    // XCD swizzle (1024 blocks)
  const int bh = sw >> 4;
  const int qb = sw & 15;
  const int q0 = qb << 7;
  const int tid = threadIdx.x, w = tid >> 6, ln = tid & 63;
  const int lg = ln >> 4, lc = ln & 15;
  const int b = bh >> 4, h = bh & 15;

  // Q fragments in registers (B-operand layout of swapped mfma == old A-operand layout)
  bf16x8 qf[2][4];
  {
    const unsigned short* qp = q_ws + ((size_t)bh * 2048 + q0 + w * 32) * 128;
#pragma unroll
    for (int m = 0; m < 2; ++m)
#pragma unroll
      for (int ks = 0; ks < 4; ++ks)
        qf[m][ks] = *(const bf16x8*)&qp[(m * 16 + lc) * 128 + ks * 32 + lg * 8];
  }

  float lsum[2] = {0.f, 0.f};
  f32x4 o[2][8] = {};   // O^T: rows d (n8,lg,r), cols q (m,lc)

  auto STAGE = [&](int bf, int kv0) {
#pragma unroll
    for (int i = 0; i < 4; ++i) {
      int rowK = w * 16 + i * 4 + lg;
      int gK = (lc * 16) ^ ((rowK & 7) << 4);
      gload16(k_ws + ((size_t)bh * 2048 + kv0 + rowK) * 128 + (gK >> 1),
              &K_lds[bf][(w * 16 + i * 4) * 128]);
      int rowV = w * 32 + i * 8 + (ln >> 3);
      int gV = ((ln & 7) * 16) ^ ((rowV & 7) << 4);
      gload16(v_wst + ((size_t)bh * 128 + rowV) * 2048 + kv0 + (gV >> 1),
              &Vt_lds[bf][(w * 32 + i * 8) * 64]);
    }
  };

  const int ntiles = (q0 >> 6) + 2;
  STAGE(0, 0);
  const float scl = 0.08838834764831845f;  // 1/sqrt(128)

  for (int t = 0; t < ntiles; ++t) {
    const int kv0 = t << 6;
    __syncthreads();                         // buf[t&1] staged for all waves
    if (t + 1 < ntiles) STAGE((t + 1) & 1, (t + 1) << 6);
    if (kv0 > q0 + w * 32 + 31) continue;    // tile fully masked for this wave
    const unsigned short* Kl = K_lds[t & 1];
    const unsigned short* Vl = Vt_lds[t & 1];

    // ---- S^T = K Q^T : lane holds kv = n*16+lg*4+r, q = m*16+lc ----
    f32x4 s[2][4] = {};
#pragma unroll
    for (int ks = 0; ks < 4; ++ks) {
      bf16x8 kb[4];
#pragma unroll
      for (int n = 0; n < 4; ++n) {
        int row = n * 16 + lc;
        int cb = (ks * 64 + lg * 16) ^ ((row & 7) << 4);
        kb[n] = *(const bf16x8*)((const char*)Kl + row * 256 + cb);
      }
#pragma unroll
      for (int m = 0; m < 2; ++m)
#pragma unroll
        for (int n = 0; n < 4; ++n)
          s[m][n] = __builtin_amdgcn_mfma_f32_16x16x32_bf16(kb[n], qf[m][ks], s[m][n], 0, 0, 0);
    }

    // ---- mask + exp (fixed max) + per-lane partial row sums + P -> LDS (b64) ----
#pragma unroll
    for (int m = 0; m < 2; ++m) {
      const int rowg = q0 + w * 32 + m * 16 + lc;
      const int prow = w * 32 + m * 16 + lc;
      const unsigned swz = (unsigned)((prow & 7) << 4);
#pragma unroll
      for (int n = 0; n < 4; ++n) {
        const int colg = kv0 + n * 16 + lg * 4;
        float p0 = (colg + 0 > rowg) ? 0.f : __expf(s[m][n][0] * scl);
        float p1 = (colg + 1 > rowg) ? 0.f : __expf(s[m][n][1] * scl);
        float p2 = (colg + 2 > rowg) ? 0.f : __expf(s[m][n][2] * scl);
        float p3 = (colg + 3 > rowg) ? 0.f : __expf(s[m][n][3] * scl);
        lsum[m] += (p0 + p1) + (p2 + p3);
        ushort4 pk;
        pk.x = f2bf(p0); pk.y = f2bf(p1); pk.z = f2bf(p2); pk.w = f2bf(p3);
        *(ushort4*)((char*)P_lds + prow * 128 + ((unsigned)(n * 32 + lg * 8) ^ swz)) = pk;
      }
    }

    // ---- O^T += V^T P^T ----
#pragma unroll
    for (int ks = 0; ks < 2; ++ks) {
      bf16x8 pbf[2], vb[8];
#pragma unroll
      for (int m = 0; m < 2; ++m) {
        int prow = w * 32 + m * 16 + lc;
        int cb = (ks * 64 + lg * 16) ^ ((prow & 7) << 4);
        pbf[m] = *(const bf16x8*)((const char*)P_lds + prow * 128 + cb);
      }
#pragma unroll
      for (int n8 = 0; n8 < 8; ++n8) {
        int row = n8 * 16 + lc;
        int cb = (ks * 64 + lg * 16) ^ ((row & 7) << 4);
        vb[n8] = *(const bf16x8*)((const char*)Vl + row * 128 + cb);
      }
#pragma unroll
      for (int m = 0; m < 2; ++m)
#pragma unroll
        for (int n8 = 0; n8 < 8; ++n8)
          o[m][n8] = __builtin_amdgcn_mfma_f32_16x16x32_bf16(vb[n8], pbf[m], o[m][n8], 0, 0, 0);
    }
  }

  // ---- final row-sum reduce + normalize + write y_ws (contiguous ushort4) ----
  float inv[2];
#pragma unroll
  for (int m = 0; m < 2; ++m) {
    float ls = lsum[m];
    ls += __shfl_xor(ls, 16);
    ls += __shfl_xor(ls, 32);
    inv[m] = 1.f / ls;
  }
  const size_t bb = (size_t)b * 2048;
#pragma unroll
  for (int m = 0; m < 2; ++m) {
    int rowg = q0 + w * 32 + m * 16 + lc;
    unsigned short* yp = y_ws + (bb + rowg) * 2048 + h * 128;
#pragma unroll
    for (int n8 = 0; n8 < 8; ++n8) {
      ushort4 pk;
      pk.x = f2bf(o[m][n8][0] * inv[m]);
      pk.y = f2bf(o[m][n8][1] * inv[m]);
      pk.z = f2bf(o[m][n8][2] * inv[m]);
      pk.w = f2bf(o[m][n8][3] * inv[m]);
      *(ushort4*)&yp[n8 * 16 + lg * 4] = pk;
    }
  }
}

// ---------------- launch ----------------
extern "C" void kernel_launch(void* const* d_in, const int* in_sizes, int n_in,
                              void* d_out, int out_size, void* d_ws, size_t ws_size,
                              hipStream_t stream) {
  const float* x    = (const float*)d_in[0];
  const float* Wqkv = (const float*)d_in[1];
  const float* bqkv = (const float*)d_in[2];
  const float* Wout = (const float*)d_in[3];
  const float* bout = (const float*)d_in[4];

  float* y_out = (float*)d_out;                       // [4,2048,2048]
  float* k_out = y_out + (size_t)16777216;            // [4,16,2048,128]
  float* v_out = y_out + (size_t)33554432;            // [4,16,2048,128]

  unsigned short* xb    = (unsigned short*)d_ws;      // 16,777,216
  unsigned short* wqkvb = xb + 16777216;              // 12,582,912
  unsigned short* woutb = wqkvb + 12582912;           //  4,194,304
  unsigned short* q_ws  = woutb + 4194304;            // 16,777,216  [bh][t][d]
  unsigned short* k_ws  = q_ws + 16777216;            // 16,777,216  [bh][t][d]
  unsigned short* v_wst = k_ws + 16777216;            // 16,777,216  [bh][d][t]
  unsigned short* y_ws  = v_wst + 16777216;           // 16,777,216  [b][t][c]

  cvt_bf16<<<2048, 256, 0, stream>>>(x, xb, 16777216 / 4);
  cvt_bf16<<<2048, 256, 0, stream>>>(Wqkv, wqkvb, 12582912 / 4);
  cvt_bf16<<<1024, 256, 0, stream>>>(Wout, woutb, 4194304 / 4);

  gemm_bt<1><<<768, 512, 0, stream>>>(xb, wqkvb, bqkv, nullptr,
                                      q_ws, k_ws, v_wst, k_out, v_out,
                                      8192, 6144, 2048);

  attn_fwd<<<1024, 256, 0, stream>>>(q_ws, k_ws, v_wst, y_ws);

  gemm_bt<0><<<256, 512, 0, stream>>>(y_ws, woutb, bout, y_out,
                                      nullptr, nullptr, nullptr, nullptr, nullptr,
                                      8192, 2048, 2048);
}